// Round 10
// baseline (245.368 us; speedup 1.0000x reference)
//
#include <hip/hip_runtime.h>
#include <stdint.h>

// B=16, H=180, W=240, N=8M events of 5 floats (x,y,t,p,b), b sorted.
constexpr int NB    = 16;
constexpr int NH    = 180;
constexpr int NW    = 240;
constexpr int FULL  = NB * NH * NW;         // 691200
constexpr int SEG   = (NH / 2) * (NW / 2);  // 10800
constexpr int HALF  = NB * SEG;             // 172800
constexpr int CELLS = NH * NW;              // 43200 full-res cells per batch
constexpr int H4W   = CELLS / 8;            // 5400 words, 4-bit packed counts
constexpr int EVT   = 1024;                 // threads per event block
constexpr int NBPB  = 16;                   // event blocks per batch (batch-aligned)
constexpr int NBLK  = NB * NBPB;            // 256 event blocks (1/CU)
constexpr int RT    = 43;                   // reduce tiles per batch (43*256 >= SEG)
constexpr int TSX   = SEG + 60;             // ts extended: cells 10800..10859 = bleed row
constexpr int TSW   = SEG / 2;              // 5400 words: bf16x2-packed ts scratch per block

// ---- fast-path ws layout (4-byte words): NOTHING needs pre-zeroing ----
constexpr int O_TMAXB = 0;                  // f32[NBLK] per-block tmax (plain stores)
constexpr int O_BLDP  = NBLK;               // f32[NBLK][60] per-block bleed stripes
constexpr int O_PRIV  = O_BLDP + NBLK * 60; // h4[NBLK][5400] then tsb16[NBLK][5400]
// ---- fallback layout (R1-style; needs zeroing) ----
constexpr int FB_TMAX  = 0;                 // u32[16]
constexpr int FB_BLEED = 16;                // f32[HALF]
constexpr int FB_CONT  = FB_BLEED + HALF;   // u32[FULL]
constexpr int FB_TSUM  = FB_CONT + FULL;    // f32[HALF]
constexpr int FB_CNT   = FB_TSUM + HALF;    // u32[HALF]
constexpr int ZFALL    = FB_CNT + HALF;     // ~4.8 MB

__device__ __forceinline__ unsigned bf16rne(float f) {  // float -> bf16 bits (RNE)
    unsigned u = __float_as_uint(f);
    return (u + 0x7fffu + ((u >> 16) & 1u)) >> 16;
}

// Single event pass, batch-aligned ranges: block k serves batch k/16, slice
// k%16 -> every event is own-batch (R5: boundary blocks straggled 2.5x).
// Init-free (R9): lanes 0-1 binary-search [sb,eb) while others zero LDS; all
// outputs private per-block. R10: 16-event super-groups = 20 float4 loads in
// flight (attacks the remaining 2x latency-exposure gap); ts scratch dumped
// as packed bf16x2 (halves the largest scratch stream; err ~0.2% << 1.6 thr).
__global__ __launch_bounds__(EVT) void k_merged(const float* __restrict__ ev, int n,
                                                unsigned int* __restrict__ ws,
                                                unsigned int* __restrict__ h4p,
                                                unsigned int* __restrict__ tsb) {
    float* tmax_blk = (float*)(ws + O_TMAXB);
    float* bleed_p  = (float*)(ws + O_BLDP);

    __shared__ unsigned int h4[H4W];    // 21.6 KB: 43200 4-bit counters
    __shared__ float        ts[TSX];    // 43.4 KB (incl 60-cell bleed row)
    __shared__ int          sbe[2];
    __shared__ unsigned int bsm;        // block tmax (float bits, t>=0)
    int tid = threadIdx.x;
    int b0 = blockIdx.x / NBPB;         // this block's batch (exact)
    int r  = blockIdx.x - b0 * NBPB;

    if (tid < 2) {                      // bnd search: first i with ev[5i+4] >= b0+tid
        int target = b0 + tid;
        int lo = 0, hi = n;
        while (lo < hi) {
            int mid = (lo + hi) >> 1;
            float v = ev[(size_t)5 * mid + 4];
            if (v < (float)target) lo = mid + 1; else hi = mid;
        }
        sbe[tid] = lo;
    } else {                            // meanwhile: vectorized LDS zero
        uint4 z = {0u, 0u, 0u, 0u};
        uint4* h4v = (uint4*)h4;
        uint4* tsv = (uint4*)ts;
        int t2 = tid - 2;
        for (int i = t2; i < H4W / 4; i += EVT - 2) h4v[i] = z;
        for (int i = t2; i < SEG / 4; i += EVT - 2) tsv[i] = z;
        if (t2 < TSX - SEG) ts[SEG + t2] = 0.0f;
        if (tid == 2) bsm = 0u;
    }
    __syncthreads();

    int sb = sbe[0], eb = sbe[1];
    long long len = (long long)(eb - sb);
    int s = sb + (int)(len * r / NBPB);
    int e = sb + (int)(len * (r + 1) / NBPB);

    float tloc = 0.0f;  // t >= 0

    auto proc = [&](float fx, float fy, float t) {
        int xi = (int)fx, yi = (int)fy;
        int cell = xi + NW * yi;
        int loc  = (xi >> 1) + (NW / 4) * yi;   // <= 10859, always in ts[]
        tloc = fmaxf(tloc, t);
        atomicAdd(&h4[cell >> 3], 1u << ((cell & 7) * 4));
        atomicAdd(&ts[loc], t);
    };

    if (s < e) {
        int as_ = min((s + 3) & ~3, e);          // align to 4 for float4 view
        for (int i = s + tid; i < as_; i += EVT) {   // <=3 prologue events
            const float* rr = ev + (size_t)5 * i;
            proc(rr[0], rr[1], rr[2]);
        }
        int ng = (e - as_) >> 2;                 // full groups of 4 events
        const float4* e4 = (const float4*)ev;
        size_t qbase = (size_t)5 * (size_t)(as_ >> 2);
        // [x0 y0 t0 p0][b0 x1 y1 t1][p1 b1 x2 y2][t2 p2 b2 x3][y3 t3 p3 b3]
        int g = tid;
        for (; g + 3 * EVT < ng; g += 4 * EVT) {     // 16 events: 20 loads in flight
            float4 q[4][5];
#pragma unroll
            for (int u = 0; u < 4; ++u) {
                size_t qb = qbase + (size_t)5 * (g + u * EVT);
#pragma unroll
                for (int w = 0; w < 5; ++w) q[u][w] = e4[qb + w];
            }
#pragma unroll
            for (int u = 0; u < 4; ++u) {
                proc(q[u][0].x, q[u][0].y, q[u][0].z);
                proc(q[u][1].y, q[u][1].z, q[u][1].w);
                proc(q[u][2].z, q[u][2].w, q[u][3].x);
                proc(q[u][3].w, q[u][4].x, q[u][4].y);
            }
        }
        for (; g < ng; g += EVT) {                   // remaining groups
            size_t qb = qbase + (size_t)5 * g;
            float4 q0 = e4[qb], q1 = e4[qb + 1], q2 = e4[qb + 2],
                   q3 = e4[qb + 3], q4 = e4[qb + 4];
            proc(q0.x, q0.y, q0.z);
            proc(q1.y, q1.z, q1.w);
            proc(q2.z, q2.w, q3.x);
            proc(q3.w, q4.x, q4.y);
        }
        for (int i = as_ + (ng << 2) + tid; i < e; i += EVT) {  // <=3 tail events
            const float* rr = ev + (size_t)5 * i;
            proc(rr[0], rr[1], rr[2]);
        }
    }

    // per-wave tmax -> one LDS atomic per wave -> one plain store per block
#pragma unroll
    for (int o = 32; o > 0; o >>= 1) tloc = fmaxf(tloc, __shfl_xor(tloc, o));
    if ((tid & 63) == 0) atomicMax(&bsm, __float_as_uint(tloc));
    __syncthreads();

    {   // dump: h4 as uint4; ts packed bf16x2 (word i = cells 2i, 2i+1)
        const uint4* h4v = (const uint4*)h4;
        uint4* dh = (uint4*)(h4p + (size_t)blockIdx.x * H4W);
        for (int i = tid; i < H4W / 4; i += EVT) dh[i] = h4v[i];
        unsigned int* dt = tsb + (size_t)blockIdx.x * TSW;
        for (int i = tid; i < TSW; i += EVT)
            dt[i] = bf16rne(ts[2 * i]) | (bf16rne(ts[2 * i + 1]) << 16);
    }
    // private bleed stripe (zeros included -> fully initialized, no pre-zero)
    if (tid < 60) bleed_p[blockIdx.x * 60 + tid] = ts[SEG + tid];
    if (tid == 0) tmax_blk[blockIdx.x] = __uint_as_float(bsm);
}

// Merge the 16 per-batch private hists; derive counter from container; reduce
// per-block tmax/bleed privates; emit all 5 outputs.
__global__ __launch_bounds__(256) void k_reduce(const unsigned int* __restrict__ ws,
                                                const unsigned int* __restrict__ h4p,
                                                const unsigned int* __restrict__ tsb,
                                                float* __restrict__ out) {
    const float* tmax_blk = (const float*)(ws + O_TMAXB);
    const float* bleed_p  = (const float*)(ws + O_BLDP);

    __shared__ float stm[2];
    int tid  = threadIdx.x;
    int b    = blockIdx.x / RT;
    int tile = blockIdx.x - b * RT;

    if (tid < 32) {                      // tmax for batch b (lanes 0-15) and b-1 (16-31)
        int which = tid >> 4;
        int k = tid & 15;
        int bb = b - which;
        float v = (bb >= 0) ? tmax_blk[bb * NBPB + k] : 0.0f;
#pragma unroll
        for (int o = 8; o > 0; o >>= 1) v = fmaxf(v, __shfl_xor(v, o));
        if (k == 0) stm[which] = v;
    }
    __syncthreads();

    int rem = tile * 256 + tid;
    if (rem >= SEG) return;
    int v = b * SEG + rem;
    int i = rem / (NW / 2);
    int j = rem - i * (NW / 2);
    int cbl = 480 * i + 2 * j;           // local cell of C[2i][2j]
    int cbg = CELLS * b + cbl;

    unsigned c00 = 0, c01 = 0, c10 = 0, c11 = 0, oc = 0;
    float tsum = 0.0f, bl = 0.0f;

    // counter[b,i,j] = C[b,2i,2j]+C[b,2i,2j+1] + odd-row shifted pair:
    //   j>=60        -> C[b,2i+1,2j-120..]
    //   j<60 && i>=1 -> C[b,2i-1,2j+120..]
    //   j<60 && i==0 -> C[b-1,179,2j+120..] (prev-batch bleed; none for b==0)
    bool prev = false;
    int ocell;
    if (j >= 60)      ocell = cbl + 120;
    else if (i >= 1)  ocell = cbl - 120;
    else { prev = true; ocell = 43080 + 2 * j; }

    int w0i = cbl >> 3, nib = (cbl & 7) * 4;   // cbl even -> pair in one word
    int w1i = w0i + 30;                        // +240 cells = +30 words
    int owi = ocell >> 3, onib = (ocell & 7) * 4;
    int twi = rem >> 1, tsh = (rem & 1) * 16;  // bf16x2 word / half select

    int base = b * NBPB;
#pragma unroll
    for (int k = 0; k < NBPB; ++k) {
        const unsigned int* hp = h4p + (size_t)(base + k) * H4W;
        unsigned w0 = hp[w0i], w1 = hp[w1i], wo = hp[owi];
        unsigned tw = tsb[(size_t)(base + k) * TSW + twi];
        c00 += (w0 >> nib) & 15u;  c01 += (w0 >> (nib + 4)) & 15u;
        c10 += (w1 >> nib) & 15u;  c11 += (w1 >> (nib + 4)) & 15u;
        oc  += ((wo >> onib) & 15u) + ((wo >> (onib + 4)) & 15u);
        tsum += __uint_as_float(((tw >> tsh) & 0xffffu) << 16);
    }
    if (prev) {
        oc = 0;                               // fast-loop oc was for batch b; discard
        if (b >= 1) {
            int pb = (b - 1) * NBPB;
#pragma unroll
            for (int k = 0; k < NBPB; ++k) {
                unsigned wo = h4p[(size_t)(pb + k) * H4W + owi];
                oc += ((wo >> onib) & 15u) + ((wo >> (onib + 4)) & 15u);
                bl += bleed_p[(pb + k) * 60 + j];   // j == rem < 60 here
            }
        }
    }
    unsigned cnt = c00 + c01 + oc;

    out[cbg]          = (float)c00;
    out[cbg + 1]      = (float)c01;
    out[cbg + NW]     = (float)c10;
    out[cbg + NW + 1] = (float)c11;
    out[FULL + v] = (float)cnt;

    float tm = stm[0];
    if (!(tm > 0.0f)) tm = 1.0f;                       // empty-batch guard
    float tmp = stm[1];
    if (!(tmp > 0.0f)) tmp = 1.0f;
    float s = tsum / tm + bl / tmp;
    out[FULL + HALF + v] = s / (float)(cnt == 0 ? 1u : cnt);

    out[FULL + 2 * HALF + v] = (float)((int)c00 - (int)c01 + (int)c10 - (int)c11);
    out[FULL + 3 * HALF + v] = (float)((int)c00 + (int)c01 - (int)c10 - (int)c11);
}

// ---------------- fallback (global-atomic R1 path; ws too small) ----------------

__global__ __launch_bounds__(256) void f_init(unsigned int* __restrict__ ws, int bound) {
    int i = blockIdx.x * 256 + threadIdx.x;
    int stride = gridDim.x * 256;
    for (; i < bound; i += stride) ws[i] = 0u;
}

__global__ __launch_bounds__(256) void f_events(const float* __restrict__ ev, int n,
                                                unsigned int* __restrict__ ws) {
    unsigned int* tmaxb = ws + FB_TMAX;
    int*   cont  = (int*)(ws + FB_CONT);
    int*   cnt   = (int*)(ws + FB_CNT);
    float* tsum  = (float*)(ws + FB_TSUM);
    float* bleed = (float*)(ws + FB_BLEED);
    __shared__ unsigned int smax[NB];
    if (threadIdx.x < NB) smax[threadIdx.x] = 0u;
    __syncthreads();
    int chunk = (n + gridDim.x - 1) / (int)gridDim.x;
    int start = blockIdx.x * chunk;
    int end   = min(start + chunk, n);
    for (int i = start + (int)threadIdx.x; i < end; i += (int)blockDim.x) {
        const float* r = ev + (size_t)5 * (size_t)i;
        int xi = (int)r[0], yi = (int)r[1], bi = (int)r[4];
        float t = r[2];
        atomicMax(&smax[bi], __float_as_uint(t));
        atomicAdd(&cont[xi + NW * yi + CELLS * bi], 1);
        int loc = (xi >> 1) + (NW / 4) * yi;
        int ik  = loc + SEG * bi;
        if (ik < HALF) {
            atomicAdd(&cnt[ik], 1);
            if (loc >= SEG) atomicAdd(&bleed[ik], t);
            else            atomicAdd(&tsum[ik], t);
        }
    }
    __syncthreads();
    if (threadIdx.x < NB) {
        unsigned v = smax[threadIdx.x];
        if (v) atomicMax(&tmaxb[threadIdx.x], v);
    }
}

__global__ __launch_bounds__(256) void f_epilogue(const unsigned int* __restrict__ ws,
                                                  float* __restrict__ out) {
    const unsigned int* tmaxb = ws + FB_TMAX;
    const int*   cont  = (const int*)(ws + FB_CONT);
    const int*   cnt   = (const int*)(ws + FB_CNT);
    const float* tsum  = (const float*)(ws + FB_TSUM);
    const float* bleed = (const float*)(ws + FB_BLEED);
    int v = blockIdx.x * blockDim.x + threadIdx.x;
    if (v >= HALF) return;
    int b   = v / SEG;
    int rem = v - b * SEG;
    int i   = rem / (NW / 2);
    int j   = rem - i * (NW / 2);
    int cbase = b * CELLS + 480 * i + 2 * j;
    int c00 = cont[cbase],      c01 = cont[cbase + 1];
    int c10 = cont[cbase + NW], c11 = cont[cbase + NW + 1];
    out[cbase]          = (float)c00;
    out[cbase + 1]      = (float)c01;
    out[cbase + NW]     = (float)c10;
    out[cbase + NW + 1] = (float)c11;
    int c = cnt[v];
    out[FULL + v] = (float)c;
    float tm  = __uint_as_float(tmaxb[b]);
    if (!(tm > 0.0f)) tm = 1.0f;
    float tmp = (b > 0) ? __uint_as_float(tmaxb[b - 1]) : 1.0f;
    if (!(tmp > 0.0f)) tmp = 1.0f;
    float s   = tsum[v] / tm + bleed[v] / tmp;
    out[FULL + HALF + v] = s / (float)(c == 0 ? 1 : c);
    out[FULL + 2 * HALF + v] = (float)(c00 - c01 + c10 - c11);
    out[FULL + 3 * HALF + v] = (float)(c00 + c01 - c10 - c11);
}

extern "C" void kernel_launch(void* const* d_in, const int* in_sizes, int n_in,
                              void* d_out, int out_size, void* d_ws, size_t ws_size,
                              hipStream_t stream) {
    const float* ev = (const float*)d_in[0];
    int n = in_sizes[0] / 5;
    unsigned int* ws = (unsigned int*)d_ws;
    float* out = (float*)d_out;

    size_t need = (size_t)(O_PRIV + NBLK * (H4W + TSW)) * 4u;  // ~11.2 MB

    if (ws_size >= need && n > 0) {
        unsigned int* h4p = ws + O_PRIV;
        unsigned int* tsb = ws + O_PRIV + NBLK * H4W;
        hipLaunchKernelGGL(k_merged, dim3(NBLK), dim3(EVT), 0, stream, ev, n, ws, h4p, tsb);
        hipLaunchKernelGGL(k_reduce, dim3(NB * RT), dim3(256), 0, stream, ws, h4p, tsb, out);
    } else {
        hipLaunchKernelGGL(f_init, dim3(512), dim3(256), 0, stream, ws, ZFALL);
        hipLaunchKernelGGL(f_events, dim3(2048), dim3(256), 0, stream, ev, n, ws);
        hipLaunchKernelGGL(f_epilogue, dim3((HALF + 255) / 256), dim3(256), 0, stream, ws, out);
    }
}